// Round 1
// baseline (285.528 us; speedup 1.0000x reference)
//
#include <hip/hip_runtime.h>

// SpecNCutout: out = select(mask, mean(x), x)
// x: (B=128, H=256, W=1024, C=1) fp32. mask = union of 5 clipped rects/batch.
// Memory-bound: floor = read 128 MiB + write 128 MiB ~= 41 us @ 6.3 TB/s.
// Two passes (mean must complete before any output): reduce, then apply.
// x fits in 256 MiB L3, so pass-2 re-read of x should mostly hit L3.

#define BB 128
#define HH 256
#define WW 1024
#define N_HOLES 5
#define HOLE_MINW (WW / 10)   // 102
#define HOLE_MINH (HH / 10)   // 25
#define N_ELEM (BB * HH * WW) // 33554432

__global__ __launch_bounds__(256) void reduce_kernel(
    const float* __restrict__ x, float* __restrict__ sum_out, int n4) {
  int tid = blockIdx.x * blockDim.x + threadIdx.x;
  int stride = gridDim.x * blockDim.x;
  const float4* x4 = (const float4*)x;
  float s = 0.0f;
  for (int i = tid; i < n4; i += stride) {
    float4 v = x4[i];
    s += (v.x + v.y) + (v.z + v.w);
  }
  // wave-64 shuffle reduce
  #pragma unroll
  for (int off = 32; off > 0; off >>= 1) s += __shfl_down(s, off, 64);
  __shared__ float wsum[4];
  int lane = threadIdx.x & 63;
  int wave = threadIdx.x >> 6;
  if (lane == 0) wsum[wave] = s;
  __syncthreads();
  if (threadIdx.x == 0) {
    float t = (wsum[0] + wsum[1]) + (wsum[2] + wsum[3]);
    atomicAdd(sum_out, t);
  }
}

__global__ __launch_bounds__(256) void apply_kernel(
    const float* __restrict__ x,
    const int* __restrict__ xs, const int* __restrict__ ys,
    const int* __restrict__ xs_w_raw, const int* __restrict__ ys_h_raw,
    const float* __restrict__ act_rand,
    const float* __restrict__ sum_ptr,
    float* __restrict__ out) {
  int row = blockIdx.x;       // row = b*H + h
  int b = row >> 8;           // H = 256
  int h = row & 255;

  float mean = sum_ptr[0] * (1.0f / (float)N_ELEM);

  // Per-row w-intervals for the 5 holes (block-uniform; empty => lo>hi).
  int lo[N_HOLES], hi[N_HOLES];
  #pragma unroll
  for (int n = 0; n < N_HOLES; ++n) {
    int base = b * N_HOLES + n;
    int cx = xs[base];
    int cy = ys[base];
    int hw = (xs_w_raw[base] + HOLE_MINW) >> 1;  // xs_w // 2 (positive)
    int hh = (ys_h_raw[base] + HOLE_MINH) >> 1;  // ys_h // 2
    int ys_s = min(max(cy - hh, 0), HH - 2);
    int ys_e = min(max(cy + hh, 1), HH - 1);
    bool act = act_rand[base] < 1.0f;            // PROB = 1.0
    bool in_row = act && (ys_s <= h) && (h <= ys_e);
    int xs_s = min(max(cx - hw, 0), WW - 2);
    int xs_e = min(max(cx + hw, 1), WW - 1);
    lo[n] = in_row ? xs_s : 1;
    hi[n] = in_row ? xs_e : 0;                   // empty interval if inactive
  }

  int w0 = (int)threadIdx.x * 4;                 // W=1024 = 256 threads * 4
  long idx = (long)row * WW + w0;
  float4 v = *(const float4*)(x + idx);
  float r[4] = {v.x, v.y, v.z, v.w};
  #pragma unroll
  for (int j = 0; j < 4; ++j) {
    int w = w0 + j;
    bool m = false;
    #pragma unroll
    for (int n = 0; n < N_HOLES; ++n)
      m = m || ((lo[n] <= w) && (w <= hi[n]));
    if (m) r[j] = mean;
  }
  float4 o;
  o.x = r[0]; o.y = r[1]; o.z = r[2]; o.w = r[3];
  *(float4*)(out + idx) = o;
}

extern "C" void kernel_launch(void* const* d_in, const int* in_sizes, int n_in,
                              void* d_out, int out_size, void* d_ws, size_t ws_size,
                              hipStream_t stream) {
  const float* x        = (const float*)d_in[0];
  const int* xs         = (const int*)d_in[1];
  const int* ys         = (const int*)d_in[2];
  const int* xs_w_raw   = (const int*)d_in[3];
  const int* ys_h_raw   = (const int*)d_in[4];
  const float* act_rand = (const float*)d_in[5];
  float* out = (float*)d_out;
  float* dsum = (float*)d_ws;

  hipMemsetAsync(dsum, 0, sizeof(float), stream);

  int n4 = N_ELEM / 4;
  reduce_kernel<<<2048, 256, 0, stream>>>(x, dsum, n4);
  apply_kernel<<<BB * HH, 256, 0, stream>>>(x, xs, ys, xs_w_raw, ys_h_raw,
                                            act_rand, dsum, out);
}

// Round 2
// 268.461 us; speedup vs baseline: 1.0636x; 1.0636x over previous
//
#include <hip/hip_runtime.h>

// SpecNCutout: out = select(mask, mean(x), x)
// x: (B=128, H=256, W=1024, C=1) fp32. mask = union of 5 clipped rects/batch.
// Memory-bound: floor = read 128 MiB (reduce) + read+write 256 MiB (apply)
// ~= 60 us @ 6.5 TB/s, minus L3 absorption of the pass-2 re-read.
// R1 change: removed single-address atomicAdd contention (2048 blocks
// bursting device-scope float atomics on one line was the suspected ~200us)
// and the 4-byte memset. Now: partials array -> 1-block finalize -> apply.

#define BB 128
#define HH 256
#define WW 1024
#define N_HOLES 5
#define HOLE_MINW (WW / 10)   // 102
#define HOLE_MINH (HH / 10)   // 25
#define N_ELEM (BB * HH * WW) // 33554432
#define RED_BLOCKS 2048

__global__ __launch_bounds__(256) void reduce_kernel(
    const float* __restrict__ x, float* __restrict__ partials) {
  int tid = blockIdx.x * blockDim.x + threadIdx.x;
  int stride = gridDim.x * blockDim.x;          // 524288
  const float4* x4 = (const float4*)x;
  const int n4 = N_ELEM / 4;                    // 8388608
  float s = 0.0f;
  for (int i = tid; i < n4; i += stride) {      // 16 iters
    float4 v = x4[i];
    s += (v.x + v.y) + (v.z + v.w);
  }
  #pragma unroll
  for (int off = 32; off > 0; off >>= 1) s += __shfl_down(s, off, 64);
  __shared__ float wsum[4];
  int lane = threadIdx.x & 63;
  int wave = threadIdx.x >> 6;
  if (lane == 0) wsum[wave] = s;
  __syncthreads();
  if (threadIdx.x == 0)
    partials[blockIdx.x] = (wsum[0] + wsum[1]) + (wsum[2] + wsum[3]);
}

__global__ __launch_bounds__(256) void finalize_kernel(
    const float* __restrict__ partials, float* __restrict__ mean_out) {
  float s = 0.0f;
  for (int i = threadIdx.x; i < RED_BLOCKS; i += 256) s += partials[i];
  #pragma unroll
  for (int off = 32; off > 0; off >>= 1) s += __shfl_down(s, off, 64);
  __shared__ float wsum[4];
  int lane = threadIdx.x & 63;
  int wave = threadIdx.x >> 6;
  if (lane == 0) wsum[wave] = s;
  __syncthreads();
  if (threadIdx.x == 0) {
    float t = (wsum[0] + wsum[1]) + (wsum[2] + wsum[3]);
    mean_out[0] = t * (1.0f / (float)N_ELEM);
  }
}

__global__ __launch_bounds__(256) void apply_kernel(
    const float* __restrict__ x,
    const int* __restrict__ xs, const int* __restrict__ ys,
    const int* __restrict__ xs_w_raw, const int* __restrict__ ys_h_raw,
    const float* __restrict__ act_rand,
    const float* __restrict__ mean_ptr,
    float* __restrict__ out) {
  int row = blockIdx.x;       // row = b*H + h
  int b = row >> 8;           // H = 256
  int h = row & 255;

  float mean = mean_ptr[0];

  // Per-row w-intervals for the 5 holes (block-uniform; empty => lo>hi).
  int lo[N_HOLES], hi[N_HOLES];
  #pragma unroll
  for (int n = 0; n < N_HOLES; ++n) {
    int base = b * N_HOLES + n;
    int cx = xs[base];
    int cy = ys[base];
    int hw = (xs_w_raw[base] + HOLE_MINW) >> 1;  // xs_w // 2 (positive)
    int hh = (ys_h_raw[base] + HOLE_MINH) >> 1;  // ys_h // 2
    int ys_s = min(max(cy - hh, 0), HH - 2);
    int ys_e = min(max(cy + hh, 1), HH - 1);
    bool act = act_rand[base] < 1.0f;            // PROB = 1.0
    bool in_row = act && (ys_s <= h) && (h <= ys_e);
    int xs_s = min(max(cx - hw, 0), WW - 2);
    int xs_e = min(max(cx + hw, 1), WW - 1);
    lo[n] = in_row ? xs_s : 1;
    hi[n] = in_row ? xs_e : 0;                   // empty interval if inactive
  }

  int w0 = (int)threadIdx.x * 4;                 // W=1024 = 256 threads * 4
  long idx = (long)row * WW + w0;
  float4 v = *(const float4*)(x + idx);
  float r[4] = {v.x, v.y, v.z, v.w};
  #pragma unroll
  for (int j = 0; j < 4; ++j) {
    int w = w0 + j;
    bool m = false;
    #pragma unroll
    for (int n = 0; n < N_HOLES; ++n)
      m = m || ((lo[n] <= w) && (w <= hi[n]));
    if (m) r[j] = mean;
  }
  float4 o;
  o.x = r[0]; o.y = r[1]; o.z = r[2]; o.w = r[3];
  *(float4*)(out + idx) = o;
}

extern "C" void kernel_launch(void* const* d_in, const int* in_sizes, int n_in,
                              void* d_out, int out_size, void* d_ws, size_t ws_size,
                              hipStream_t stream) {
  const float* x        = (const float*)d_in[0];
  const int* xs         = (const int*)d_in[1];
  const int* ys         = (const int*)d_in[2];
  const int* xs_w_raw   = (const int*)d_in[3];
  const int* ys_h_raw   = (const int*)d_in[4];
  const float* act_rand = (const float*)d_in[5];
  float* out = (float*)d_out;

  float* partials = (float*)d_ws;                // RED_BLOCKS floats
  float* mean_ptr = partials + RED_BLOCKS;       // 1 float

  reduce_kernel<<<RED_BLOCKS, 256, 0, stream>>>(x, partials);
  finalize_kernel<<<1, 256, 0, stream>>>(partials, mean_ptr);
  apply_kernel<<<BB * HH, 256, 0, stream>>>(x, xs, ys, xs_w_raw, ys_h_raw,
                                            act_rand, mean_ptr, out);
}